// Round 15
// baseline (191.571 us; speedup 1.0000x reference)
//
#include <hip/hip_runtime.h>
#include <hip/hip_bf16.h>
#include <math.h>

#define N_TOK 2048
#define HIDDEN 2880
#define QKV_DIM 5120
#define LOG2E 1.44269504088896340736f

typedef __attribute__((ext_vector_type(8))) short short8;
typedef __attribute__((ext_vector_type(4))) float f32x4;
typedef __attribute__((ext_vector_type(16))) float f32x16;

__device__ __forceinline__ float bf2f(unsigned short u) {
  union { unsigned int i; float f; } c; c.i = ((unsigned int)u) << 16; return c.f;
}
__device__ __forceinline__ unsigned short f2bf(float f) {
  union { float f; unsigned int i; } c; c.f = f;
  unsigned int i = c.i;
  return (unsigned short)((i + 0x7FFFu + ((i >> 16) & 1u)) >> 16);
}
__device__ __forceinline__ void gload16(const void* g, void* l) {
  __builtin_amdgcn_global_load_lds((const __attribute__((address_space(1))) void*)g,
                                   (__attribute__((address_space(3))) void*)l, 16, 0, 0);
}

// ---- prep1: [transpose+cast w_qkv] + [rmsnorm] + [rope table] ----
__global__ __launch_bounds__(256) void prep1_kernel(
    const float* __restrict__ w_qkv, unsigned short* __restrict__ wqkvT,
    const float* __restrict__ x, const float* __restrict__ scale,
    unsigned short* __restrict__ t_bf,
    float* __restrict__ cstab, float* __restrict__ sntab)
{
  __shared__ float tile[64][65];
  int b = blockIdx.x;
  const int t = threadIdx.x;
  if (b >= 5648) {
    const float log_base = 11.9183905731f;   // ln(150000)
    const float low  = 32.f * logf(4096.f / (32.f * 6.283185307179586f)) / log_base;
    const float high = 32.f * logf(4096.f / 6.283185307179586f) / log_base;
    const float conc = 1.3465735903f;        // 0.1*ln(32)+1
    int e0 = (b - 5648) * 1024 + t * 4;
#pragma unroll
    for (int k = 0; k < 4; ++k) {
      int entry = e0 + k;
      int token = entry >> 5, d = entry & 31;
      float fj = (float)d;
      float extrap = expf(-log_base * fj * 0.03125f);
      float interp = extrap * 0.03125f;
      float ramp = (fj - low) / (high - low);
      float maskv = 1.f - fminf(fmaxf(ramp, 0.f), 1.f);
      float inv_freq = interp * (1.f - maskv) + extrap * maskv;
      float ang = (float)token * inv_freq;
      float s, c;
      sincosf(ang, &s, &c);
      cstab[entry] = c * conc;
      sntab[entry] = s * conc;
    }
    return;
  }
  if (b >= 3600) {
    int row = b - 3600;
    const float* xr = x + (size_t)row * HIDDEN;
    float ss = 0.f;
    for (int i = t; i < HIDDEN / 4; i += 256) {
      float4 v = ((const float4*)xr)[i];
      ss += v.x * v.x + v.y * v.y + v.z * v.z + v.w * v.w;
    }
#pragma unroll
    for (int off = 32; off; off >>= 1) ss += __shfl_down(ss, off, 64);
    __shared__ float red[4];
    if ((t & 63) == 0) red[t >> 6] = ss;
    __syncthreads();
    float total = red[0] + red[1] + red[2] + red[3];
    float rinv = rsqrtf(total / (float)HIDDEN + 1e-5f);
    for (int i = t; i < HIDDEN / 4; i += 256) {
      float4 v = ((const float4*)xr)[i];
      float4 s4 = ((const float4*)scale)[i];
      union { unsigned short u[4]; uint2 p; } pk;
      pk.u[0] = f2bf(v.x * rinv * s4.x);
      pk.u[1] = f2bf(v.y * rinv * s4.y);
      pk.u[2] = f2bf(v.z * rinv * s4.z);
      pk.u[3] = f2bf(v.w * rinv * s4.w);
      *(uint2*)&t_bf[(size_t)row * HIDDEN + i * 4] = pk.p;
    }
    return;
  }
  int bx = b % 80, by = b / 80;
  const int r0 = by * 64, c0 = bx * 64;
  const int c4 = t & 15, rr = t >> 4;
#pragma unroll
  for (int p = 0; p < 4; ++p) {
    int row = rr + p * 16;
    float4 v = *(const float4*)&w_qkv[(size_t)(r0 + row) * 5120 + c0 + c4 * 4];
    tile[row][c4 * 4 + 0] = v.x; tile[row][c4 * 4 + 1] = v.y;
    tile[row][c4 * 4 + 2] = v.z; tile[row][c4 * 4 + 3] = v.w;
  }
  __syncthreads();
  const int rc = t & 7;
#pragma unroll
  for (int it = 0; it < 2; ++it) {
    int cc = (t >> 3) + it * 32;
    unsigned short tmp[8];
#pragma unroll
    for (int i = 0; i < 8; ++i) tmp[i] = f2bf(tile[rc * 8 + i][cc]);
    *(uint4*)&wqkvT[(size_t)(c0 + cc) * 2880 + r0 + rc * 8] = *(uint4*)tmp;
  }
}

// ------- QKV: barrier-free WAVE-PRIVATE GEMM, 128x320 block = 8 x (64x80 waves) -------
// Each wave owns: 18KB LDS (A 64x64 = 8KB, B 80x64 = 10KB, single-buffered),
// its own staging (18 gload16/tile) and its 40 MFMA. NO s_barrier anywhere:
// waves self-pace, stalls decorrelate (the block-wide vmcnt(0)+barrier drain
// was the plateau: R10/R12/R13 ruled out load-wait/depth/tile-count).
// WAR safety (stage overwrites buffer): reads land in regs, then
// lgkmcnt(0)+sched_barrier(0) [rule #18] before next-tile issue.
__global__ __launch_bounds__(512, 1) void gemm_wp(
    const unsigned short* __restrict__ A,
    const unsigned short* __restrict__ Bt,
    const float* __restrict__ bias,
    unsigned short* __restrict__ Cout,
    int K, int Ncols)
{
  __shared__ char smem_[147456];             // 8 waves x 18432 B
  const int tid = threadIdx.x;
  const int lane = tid & 63;
  const int w = tid >> 6;
  const int fr = lane & 15, fq = lane >> 4;
  const int wr = w >> 2, wc = w & 3;

  // bijective XCD swizzle (256 % 8 == 0)
  const int nwg = gridDim.x;
  const int cpx = nwg >> 3;
  const int wg = (blockIdx.x & 7) * cpx + (blockIdx.x >> 3);
  const int by = wg & 15, bx = wg >> 4;
  const int arow0 = by * 128 + wr * 64;      // wave's 64 A-rows
  const int bcol0 = bx * 320 + wc * 80;      // wave's 80 B-rows
  const int wb = w * 18432;

  // ---- staging offsets: 18 chunks/tile (A: 0..7, B: 8..17), dest linear ----
  int offA[8], offB[10];
#pragma unroll
  for (int c = 0; c < 8; ++c) {
    int g = c * 64 + lane;                   // [0,512): kk|rr|u over [2][64][4]
    int kk = g >> 8, rem = g & 255, rr = rem >> 2, u = rem & 3;
    offA[c] = (arow0 + rr) * K + kk * 32 + ((u ^ ((rr >> 1) & 3)) * 8);
  }
#pragma unroll
  for (int c = 0; c < 10; ++c) {
    int g = c * 64 + lane;                   // [0,640): kk|rr|u over [2][80][4]
    int kk = g / 320, rem = g - kk * 320, rr = rem >> 2, u = rem & 3;
    offB[c] = (bcol0 + rr) * K + kk * 32 + ((u ^ ((rr >> 1) & 3)) * 8);
  }
  const int ldsA = wb + lane * 16;           // + c*1024
  const int ldsB = wb + 8192 + lane * 16;    // + c*1024
  // ---- fragment read offsets (1KB-contiguous bijection per frag: conflict-free)
  const int urd = (fq ^ ((fr >> 1) & 3)) * 16;
  const int aoff = wb + fr * 64 + urd;               // + mf*1024 + kk*4096
  const int boff = wb + 8192 + fr * 64 + urd;        // + nf*1024 + kk*5120

  f32x4 acc[4][5];
#pragma unroll
  for (int mf = 0; mf < 4; ++mf)
#pragma unroll
    for (int nf = 0; nf < 5; ++nf) acc[mf][nf] = (f32x4)0.f;

  const int NT = K >> 6;

  // ---- prologue: stage tile 0 ----
#pragma unroll
  for (int c = 0; c < 8; ++c)  gload16(A + offA[c], smem_ + ldsA + c * 1024);
#pragma unroll
  for (int c = 0; c < 10; ++c) gload16(Bt + offB[c], smem_ + ldsB + c * 1024);

  for (int t = 0; t < NT; ++t) {
    const int ktn = (t + 1) * 64;
    // own 18 loads (issued one tile-body ago, or prologue)
    asm volatile("s_waitcnt vmcnt(0)" ::: "memory");

    short8 fa[4][2], fb[5][2];
#pragma unroll
    for (int kk = 0; kk < 2; ++kk) {
#pragma unroll
      for (int mf = 0; mf < 4; ++mf)
        fa[mf][kk] = *(const short8*)(smem_ + aoff + kk * 4096 + mf * 1024);
#pragma unroll
      for (int nf = 0; nf < 5; ++nf)
        fb[nf][kk] = *(const short8*)(smem_ + boff + kk * 5120 + nf * 1024);
    }
    // fence: all ds_reads complete before overwriting the buffer
    asm volatile("s_waitcnt lgkmcnt(0)" ::: "memory");
    __builtin_amdgcn_sched_barrier(0);

    if (t + 1 < NT) {
#pragma unroll
      for (int c = 0; c < 8; ++c)  gload16(A + offA[c] + ktn, smem_ + ldsA + c * 1024);
#pragma unroll
      for (int c = 0; c < 10; ++c) gload16(Bt + offB[c] + ktn, smem_ + ldsB + c * 1024);
    }

    __builtin_amdgcn_s_setprio(1);
#pragma unroll
    for (int kk = 0; kk < 2; ++kk)
#pragma unroll
      for (int mf = 0; mf < 4; ++mf)
#pragma unroll
        for (int nf = 0; nf < 5; ++nf)
          acc[mf][nf] = __builtin_amdgcn_mfma_f32_16x16x32_bf16(fa[mf][kk], fb[nf][kk], acc[mf][nf], 0, 0, 0);
    __builtin_amdgcn_s_setprio(0);
  }

  // ---- epilogue: bf16 + bias ----
#pragma unroll
  for (int mf = 0; mf < 4; ++mf) {
#pragma unroll
    for (int nf = 0; nf < 5; ++nf) {
      const int colb = bcol0 + nf * 16 + fr;
      const int rowb = arow0 + mf * 16 + fq * 4;
      const float bs = bias[colb];
#pragma unroll
      for (int j = 0; j < 4; ++j)
        Cout[(size_t)(rowb + j) * Ncols + colb] = f2bf(acc[mf][nf][j] + bs);
    }
  }
}

// ------- out-proj: 128 x 192, BK=128 free-run GEMM (2x80KB LDS) -------
__global__ __launch_bounds__(512, 2) void gemm_o(
    const unsigned short* __restrict__ A,
    const unsigned short* __restrict__ Bt,
    const float* __restrict__ bias,
    const float* __restrict__ resid,
    float* __restrict__ Cout,
    int K, int Ncols)
{
  constexpr int NF = 3;
  constexpr int BUFSZ = 32768 + NF * 16384;  // 81920
  __shared__ char smem_[2 * BUFSZ];          // 163840
  const int tid = threadIdx.x;
  const int lane = tid & 63;
  const int w = tid >> 6;
  const int fr = lane & 15, fq = lane >> 4;
  const int wr = w >> 2, wc = w & 3;

  const int nwg = gridDim.x;
  const int cpx = nwg >> 3;
  const int wg = (blockIdx.x & 7) * cpx + (blockIdx.x >> 3);
  const int by = wg & 15, bx = wg >> 4;
  const int row0 = by * 128, col0 = bx * (NF * 64);

  const unsigned short* gsrcA[4];
  int loffA[4];
#pragma unroll
  for (int c = 0; c < 4; ++c) {
    int g = tid + 512 * c;
    int kk = g >> 9, rr = (g >> 2) & 127, u = g & 3;
    gsrcA[c] = A + (size_t)(row0 + rr) * K + kk * 32 + ((u ^ ((rr >> 1) & 3)) * 8);
    loffA[c] = kk * 8192 + rr * 64 + u * 16;
  }
  const unsigned short* gsrcB[6];
  int loffB[6];
#pragma unroll
  for (int c = 0; c < 6; ++c) {
    int g = tid + 512 * c;
    int kk = g / 768;
    int rm = g - kk * 768;
    int rr = rm >> 2, u = rm & 3;
    gsrcB[c] = Bt + (size_t)(col0 + rr) * K + kk * 32 + ((u ^ ((rr >> 1) & 3)) * 8);
    loffB[c] = 32768 + kk * 12288 + rr * 64 + u * 16;
  }
  const int urd = (fq ^ ((fr >> 1) & 3)) * 16;
  const int aoffb = (wr * 64 + fr) * 64 + urd;
  const int boffb = 32768 + (wc * 48 + fr) * 64 + urd;

  f32x4 acc[4][NF];
#pragma unroll
  for (int mf = 0; mf < 4; ++mf)
#pragma unroll
    for (int nf = 0; nf < NF; ++nf) acc[mf][nf] = (f32x4)0.f;

  const int NT = K >> 7;

#define RD_A(mf, kk) (*(const short8*)(smem_ + bufo + (kk)*8192 + (mf)*1024 + aoffb))
#define RD_B(nf, kk) (*(const short8*)(smem_ + bufo + (kk)*12288 + (nf)*1024 + boffb))

#pragma unroll
  for (int c = 0; c < 4; ++c) gload16(gsrcA[c], smem_ + loffA[c]);
#pragma unroll
  for (int c = 0; c < 6; ++c) gload16(gsrcB[c], smem_ + loffB[c]);

  for (int t = 0; t < NT; ++t) {
    const int bufo = (t & 1) * BUFSZ;
    const int nbufo = bufo ^ BUFSZ;
    const int ktn = (t + 1) * 128;
    const bool pref = (t + 1) < NT;

    asm volatile("s_waitcnt vmcnt(0)" ::: "memory");
    __builtin_amdgcn_s_barrier();

    if (pref) {
#pragma unroll
      for (int c = 0; c < 4; ++c) gload16(gsrcA[c] + ktn, smem_ + nbufo + loffA[c]);
      gload16(gsrcB[0] + ktn, smem_ + nbufo + loffB[0]);
    }

    short8 afr[4], bfr[NF];
#pragma unroll
    for (int kk = 0; kk < 4; ++kk) {
#pragma unroll
      for (int nf = 0; nf < NF; ++nf) bfr[nf] = RD_B(nf, kk);
#pragma unroll
      for (int mf = 0; mf < 4; ++mf) afr[mf] = RD_A(mf, kk);
      __builtin_amdgcn_s_setprio(1);
#pragma unroll
      for (int mf = 0; mf < 4; ++mf)
#pragma unroll
        for (int nf = 0; nf < NF; ++nf)
          acc[mf][nf] = __builtin_amdgcn_mfma_f32_16x16x32_bf16(afr[mf], bfr[nf], acc[mf][nf], 0, 0, 0);
      __builtin_amdgcn_s_setprio(0);
      if (kk == 0 && pref) {
#pragma unroll
        for (int c = 1; c < 6; ++c) gload16(gsrcB[c] + ktn, smem_ + nbufo + loffB[c]);
      }
    }
  }
#undef RD_A
#undef RD_B

#pragma unroll
  for (int mf = 0; mf < 4; ++mf) {
#pragma unroll
    for (int nf = 0; nf < NF; ++nf) {
      const int colb = col0 + wc * NF * 16 + nf * 16 + fr;
      const int rowb = row0 + wr * 64 + mf * 16 + fq * 4;
      const float bs = bias[colb];
#pragma unroll
      for (int j = 0; j < 4; ++j) {
        const size_t idx = (size_t)(rowb + j) * Ncols + colb;
        Cout[idx] = acc[mf][nf][j] + bs + resid[idx];
      }
    }
  }
}

// ---- attn (fused YaRN rope) + w_out transpose co-tenant blocks ----
__global__ __launch_bounds__(512) void attn_trans_kernel(
    const unsigned short* __restrict__ qkv, const float* __restrict__ sinks,
    const float* __restrict__ cstab, const float* __restrict__ sntab,
    unsigned short* __restrict__ attn,
    const float* __restrict__ w_out, unsigned short* __restrict__ woutT)
{
  __shared__ char smem[45056];
  const int tid = threadIdx.x;
  int bb = blockIdx.x;
  if (bb >= 512) {
    int b = bb - 512;
    int bx = b % 45, by = b / 45;
    const int r0 = by * 64, c0 = bx * 64;
    float (*tile)[65] = (float(*)[65])smem;
    const int c4 = tid & 15, rr = tid >> 4;
#pragma unroll
    for (int p = 0; p < 2; ++p) {
      int row = rr + p * 32;
      float4 v = *(const float4*)&w_out[(size_t)(r0 + row) * 2880 + c0 + c4 * 4];
      tile[row][c4 * 4 + 0] = v.x; tile[row][c4 * 4 + 1] = v.y;
      tile[row][c4 * 4 + 2] = v.z; tile[row][c4 * 4 + 3] = v.w;
    }
    __syncthreads();
    const int rc = tid & 7, cc = tid >> 3;
    unsigned short tmp[8];
#pragma unroll
    for (int i = 0; i < 8; ++i) tmp[i] = f2bf(tile[rc * 8 + i][cc]);
    *(uint4*)&woutT[(size_t)(c0 + cc) * 4096 + r0 + rc * 8] = *(uint4*)tmp;
    return;
  }
  unsigned short* Ks = (unsigned short*)smem;
  unsigned short* Vt = (unsigned short*)(smem + 20480);
  const int lane = tid & 63;
  const int w    = tid >> 6;
  const int qb = bb & 63, kvh = bb >> 6;
  const int q0 = qb * 32;
  const int kb = q0 - 128;
  const int h  = lane >> 5;
  const int ql = lane & 31;

  for (int task = tid; task < 640; task += 512) {
    int r = task >> 2, p = task & 3;
    int j = kb + r; if (j < 0) j = 0;
    const unsigned short* kp = qkv + (size_t)j * QKV_DIM + 4096 + kvh * 64 + p * 8;
    short8 klo = *(const short8*)kp;
    short8 khi = *(const short8*)(kp + 32);
    float cv[8], sv[8];
    *(float4*)&cv[0] = *(const float4*)&cstab[j * 32 + p * 8];
    *(float4*)&cv[4] = *(const float4*)&cstab[j * 32 + p * 8 + 4];
    *(float4*)&sv[0] = *(const float4*)&sntab[j * 32 + p * 8];
    *(float4*)&sv[4] = *(const float4*)&sntab[j * 32 + p * 8 + 4];
    unsigned short nlo[8], nhi[8];
#pragma unroll
    for (int e = 0; e < 8; ++e) {
      float lo = bf2f(((const unsigned short*)&klo)[e]);
      float hi = bf2f(((const unsigned short*)&khi)[e]);
      nlo[e] = f2bf(lo * cv[e] - hi * sv[e]);
      nhi[e] = f2bf(hi * cv[e] + lo * sv[e]);
    }
    *(short8*)&Ks[r * 64 + ((p ^ (r & 7)) * 8)]       = *(short8*)nlo;
    *(short8*)&Ks[r * 64 + (((p + 4) ^ (r & 7)) * 8)] = *(short8*)nhi;
  }
  for (int c = tid; c < 2560; c += 512) {
    int jl = c >> 4;
    int d4 = (c & 15) * 4;
    int j = kb + jl; if (j < 0) j = 0;
    ushort4 v4 = *(const ushort4*)&qkv[(size_t)j * QKV_DIM + 4608 + kvh * 64 + d4];
    const unsigned short* pv = (const unsigned short*)&v4;
#pragma unroll
    for (int t = 0; t < 4; ++t) {
      int d = d4 + t;
      int slot = (jl >> 3) ^ (d & 7);
      Vt[d * 192 + slot * 8 + (jl & 7)] = pv[t];
    }
  }
  const int head = kvh * 8 + w;
  const int i_q = q0 + ql;
  short8 qf[4];
  {
    const unsigned short* qp = qkv + (size_t)i_q * QKV_DIM + head * 64 + h * 8;
#pragma unroll
    for (int ks = 0; ks < 4; ++ks) qf[ks] = *(const short8*)(qp + ks * 16);
#pragma unroll
    for (int p = 0; p < 2; ++p) {
      float cv[8], sv[8];
      int o = i_q * 32 + p * 16 + h * 8;
      *(float4*)&cv[0] = *(const float4*)&cstab[o];
      *(float4*)&cv[4] = *(const float4*)&cstab[o + 4];
      *(float4*)&sv[0] = *(const float4*)&sntab[o];
      *(float4*)&sv[4] = *(const float4*)&sntab[o + 4];
      unsigned short nlo[8], nhi[8];
#pragma unroll
      for (int e = 0; e < 8; ++e) {
        float lo = bf2f(((const unsigned short*)&qf[p])[e]);
        float hi = bf2f(((const unsigned short*)&qf[p + 2])[e]);
        nlo[e] = f2bf(lo * cv[e] - hi * sv[e]);
        nhi[e] = f2bf(hi * cv[e] + lo * sv[e]);
      }
      qf[p]     = *(short8*)nlo;
      qf[p + 2] = *(short8*)nhi;
    }
  }
  __syncthreads();

  const float SC = 0.125f * LOG2E;
  f32x16 oacc0 = (f32x16)(0.f), oacc1 = (f32x16)(0.f);
  float m = -1e30f, l = 0.f;

  const int tstart = qb < 4 ? 4 - qb : 0;
  for (int tt = tstart; tt < 5; ++tt) {
    const int j0 = kb + tt * 32;
    f32x16 sacc = (f32x16)(0.f);
    const int kr = tt * 32 + ql;
#pragma unroll
    for (int ks = 0; ks < 4; ++ks) {
      short8 kf = *(const short8*)&Ks[kr * 64 + (((ks * 2 + h) ^ (kr & 7)) * 8)];
      sacc = __builtin_amdgcn_mfma_f32_32x32x16_bf16(kf, qf[ks], sacc, 0, 0, 0);
    }
    float sc16[16];
    float mt = -INFINITY;
#pragma unroll
    for (int e = 0; e < 16; ++e) {
      int kk = (e & 3) + 8 * (e >> 2) + 4 * h;
      int j = j0 + kk;
      float s2 = sacc[e] * SC;
      bool valid = (j <= i_q) && (j > i_q - 128);
      s2 = valid ? s2 : -INFINITY;
      sc16[e] = s2;
      mt = fmaxf(mt, s2);
    }
    mt = fmaxf(mt, __shfl_xor(mt, 32));
    float mnew = fmaxf(m, mt);
    float r = exp2f(m - mnew);
    l *= r;
    oacc0 *= r;
    oacc1 *= r;
    m = mnew;
    unsigned int wpk[8];
    float ls = 0.f;
#pragma unroll
    for (int e2 = 0; e2 < 8; ++e2) {
      float plo = exp2f(sc16[2 * e2]     - m);
      float phi = exp2f(sc16[2 * e2 + 1] - m);
      ls += plo + phi;
      asm("v_cvt_pk_bf16_f32 %0, %1, %2" : "=v"(wpk[e2]) : "v"(plo), "v"(phi));
    }
    l += ls;
#pragma unroll
    for (int m16 = 0; m16 < 2; ++m16) {
      int go = 2 * m16 + h;
      int gs = 2 * m16 + 1 - h;
      unsigned int x0 = (unsigned int)__shfl_xor((int)wpk[2 * gs],     32);
      unsigned int x1 = (unsigned int)__shfl_xor((int)wpk[2 * gs + 1], 32);
      union { unsigned int u[4]; short8 s; } bu;
      bu.u[0] = h ? x0 : wpk[2 * go];
      bu.u[1] = h ? x1 : wpk[2 * go + 1];
      bu.u[2] = h ? wpk[2 * go]     : x0;
      bu.u[3] = h ? wpk[2 * go + 1] : x1;
      short8 bfrag = bu.s;
#pragma unroll
      for (int dt = 0; dt < 2; ++dt) {
        int d = dt * 32 + ql;
        int slot = (tt * 4 + m16 * 2 + h) ^ (d & 7);
        short8 vf = *(const short8*)&Vt[d * 192 + slot * 8];
        if (dt == 0)
          oacc0 = __builtin_amdgcn_mfma_f32_32x32x16_bf16(vf, bfrag, oacc0, 0, 0, 0);
        else
          oacc1 = __builtin_amdgcn_mfma_f32_32x32x16_bf16(vf, bfrag, oacc1, 0, 0, 0);
      }
    }
  }
  float lt = l + __shfl_xor(l, 32);
  lt += exp2f(sinks[head] * LOG2E - m);
  float inv = 1.f / lt;
  unsigned short* op = attn + (size_t)i_q * 4096 + head * 64;
#pragma unroll
  for (int dt = 0; dt < 2; ++dt) {
#pragma unroll
    for (int g = 0; g < 4; ++g) {
      float f0, f1, f2, f3;
      if (dt == 0) {
        f0 = oacc0[4 * g]; f1 = oacc0[4 * g + 1]; f2 = oacc0[4 * g + 2]; f3 = oacc0[4 * g + 3];
      } else {
        f0 = oacc1[4 * g]; f1 = oacc1[4 * g + 1]; f2 = oacc1[4 * g + 2]; f3 = oacc1[4 * g + 3];
      }
      unsigned int u0, u1;
      asm("v_cvt_pk_bf16_f32 %0, %1, %2" : "=v"(u0) : "v"(f0 * inv), "v"(f1 * inv));
      asm("v_cvt_pk_bf16_f32 %0, %1, %2" : "=v"(u1) : "v"(f2 * inv), "v"(f3 * inv));
      int d = dt * 32 + 8 * g + 4 * h;
      uint2 pr; pr.x = u0; pr.y = u1;
      *(uint2*)(op + d) = pr;
    }
  }
}

extern "C" void kernel_launch(void* const* d_in, const int* in_sizes, int n_in,
                              void* d_out, int out_size, void* d_ws, size_t ws_size,
                              hipStream_t stream)
{
  const float* x      = (const float*)d_in[0];
  const float* nscale = (const float*)d_in[1];
  const float* w_qkv  = (const float*)d_in[2];
  const float* b_qkv  = (const float*)d_in[3];
  const float* sinks  = (const float*)d_in[4];
  const float* w_out  = (const float*)d_in[5];
  const float* b_out  = (const float*)d_in[6];

  char* ws = (char*)d_ws;
  unsigned short* t_bf  = (unsigned short*)(ws);                 // [2048][2880] bf16
  unsigned short* wqkvT = (unsigned short*)(ws + 11796480);      // [5120][2880] bf16
  unsigned short* qkv   = (unsigned short*)(ws + 41287680);      // [2048][5120] bf16
  unsigned short* attn  = (unsigned short*)(ws + 62259200);      // [2048][4096] bf16
  unsigned short* woutT = (unsigned short*)(ws + 79036416);      // [2880][4096] bf16
  float* cstab          = (float*)(ws + 102629376);              // [2048][32] f32
  float* sntab          = (float*)(ws + 102891520);              // [2048][32] f32

  prep1_kernel<<<5712, 256, 0, stream>>>(w_qkv, wqkvT, x, nscale, t_bf, cstab, sntab);
  gemm_wp<<<256, 512, 0, stream>>>(t_bf, wqkvT, b_qkv, qkv, 2880, 5120);
  attn_trans_kernel<<<3392, 512, 0, stream>>>(qkv, sinks, cstab, sntab, attn, w_out, woutT);
  gemm_o<<<240, 512, 0, stream>>>(attn, woutT, b_out, x, (float*)d_out, 4096, 2880);
}

// Round 16
// 172.267 us; speedup vs baseline: 1.1121x; 1.1121x over previous
//
#include <hip/hip_runtime.h>
#include <hip/hip_bf16.h>
#include <math.h>

#define N_TOK 2048
#define HIDDEN 2880
#define QKV_DIM 5120
#define LOG2E 1.44269504088896340736f

typedef __attribute__((ext_vector_type(8))) short short8;
typedef __attribute__((ext_vector_type(4))) float f32x4;
typedef __attribute__((ext_vector_type(16))) float f32x16;

__device__ __forceinline__ float bf2f(unsigned short u) {
  union { unsigned int i; float f; } c; c.i = ((unsigned int)u) << 16; return c.f;
}
__device__ __forceinline__ unsigned short f2bf(float f) {
  union { float f; unsigned int i; } c; c.f = f;
  unsigned int i = c.i;
  return (unsigned short)((i + 0x7FFFu + ((i >> 16) & 1u)) >> 16);
}
__device__ __forceinline__ void gload16(const void* g, void* l) {
  __builtin_amdgcn_global_load_lds((const __attribute__((address_space(1))) void*)g,
                                   (__attribute__((address_space(3))) void*)l, 16, 0, 0);
}

// ---- prep1: [transpose+cast w_qkv] + [rmsnorm] + [rope table] ----
__global__ __launch_bounds__(256) void prep1_kernel(
    const float* __restrict__ w_qkv, unsigned short* __restrict__ wqkvT,
    const float* __restrict__ x, const float* __restrict__ scale,
    unsigned short* __restrict__ t_bf,
    float* __restrict__ cstab, float* __restrict__ sntab)
{
  __shared__ float tile[64][65];
  int b = blockIdx.x;
  const int t = threadIdx.x;
  if (b >= 5648) {
    const float log_base = 11.9183905731f;   // ln(150000)
    const float low  = 32.f * logf(4096.f / (32.f * 6.283185307179586f)) / log_base;
    const float high = 32.f * logf(4096.f / 6.283185307179586f) / log_base;
    const float conc = 1.3465735903f;        // 0.1*ln(32)+1
    int e0 = (b - 5648) * 1024 + t * 4;
#pragma unroll
    for (int k = 0; k < 4; ++k) {
      int entry = e0 + k;
      int token = entry >> 5, d = entry & 31;
      float fj = (float)d;
      float extrap = expf(-log_base * fj * 0.03125f);
      float interp = extrap * 0.03125f;
      float ramp = (fj - low) / (high - low);
      float maskv = 1.f - fminf(fmaxf(ramp, 0.f), 1.f);
      float inv_freq = interp * (1.f - maskv) + extrap * maskv;
      float ang = (float)token * inv_freq;
      float s, c;
      sincosf(ang, &s, &c);
      cstab[entry] = c * conc;
      sntab[entry] = s * conc;
    }
    return;
  }
  if (b >= 3600) {
    int row = b - 3600;
    const float* xr = x + (size_t)row * HIDDEN;
    float ss = 0.f;
    for (int i = t; i < HIDDEN / 4; i += 256) {
      float4 v = ((const float4*)xr)[i];
      ss += v.x * v.x + v.y * v.y + v.z * v.z + v.w * v.w;
    }
#pragma unroll
    for (int off = 32; off; off >>= 1) ss += __shfl_down(ss, off, 64);
    __shared__ float red[4];
    if ((t & 63) == 0) red[t >> 6] = ss;
    __syncthreads();
    float total = red[0] + red[1] + red[2] + red[3];
    float rinv = rsqrtf(total / (float)HIDDEN + 1e-5f);
    for (int i = t; i < HIDDEN / 4; i += 256) {
      float4 v = ((const float4*)xr)[i];
      float4 s4 = ((const float4*)scale)[i];
      union { unsigned short u[4]; uint2 p; } pk;
      pk.u[0] = f2bf(v.x * rinv * s4.x);
      pk.u[1] = f2bf(v.y * rinv * s4.y);
      pk.u[2] = f2bf(v.z * rinv * s4.z);
      pk.u[3] = f2bf(v.w * rinv * s4.w);
      *(uint2*)&t_bf[(size_t)row * HIDDEN + i * 4] = pk.p;
    }
    return;
  }
  int bx = b % 80, by = b / 80;
  const int r0 = by * 64, c0 = bx * 64;
  const int c4 = t & 15, rr = t >> 4;
#pragma unroll
  for (int p = 0; p < 4; ++p) {
    int row = rr + p * 16;
    float4 v = *(const float4*)&w_qkv[(size_t)(r0 + row) * 5120 + c0 + c4 * 4];
    tile[row][c4 * 4 + 0] = v.x; tile[row][c4 * 4 + 1] = v.y;
    tile[row][c4 * 4 + 2] = v.z; tile[row][c4 * 4 + 3] = v.w;
  }
  __syncthreads();
  const int rc = t & 7;
#pragma unroll
  for (int it = 0; it < 2; ++it) {
    int cc = (t >> 3) + it * 32;
    unsigned short tmp[8];
#pragma unroll
    for (int i = 0; i < 8; ++i) tmp[i] = f2bf(tile[rc * 8 + i][cc]);
    *(uint4*)&wqkvT[(size_t)(c0 + cc) * 2880 + r0 + rc * 8] = *(uint4*)tmp;
  }
}

// ------- QKV: 128 x 320 free-run GEMM (R9 config, 960 TF, MfmaUtil 40%) -------
// Structural sweep closed: R10 (2 blocks/CU), R12 (2-deep prefetch),
// R13 (BK=128), R15 (barrier-free wave-private) all neutral-or-worse.
// This 2-barrier free-run config is the plain-HIP plateau for this shape.
template <int NF, int EPI>
__global__ __launch_bounds__(512, 2) void gemm8(
    const unsigned short* __restrict__ A,
    const unsigned short* __restrict__ Bt,
    const float* __restrict__ bias,
    const float* __restrict__ resid,
    void* __restrict__ Cout,
    int K, int Ncols)
{
  constexpr int BUFSZ = 16384 + NF * 8192;
  constexpr int NCH = 2 + NF;
  constexpr int HALF = NCH / 2;
  __shared__ char smem_[2 * BUFSZ];
  const int tid = threadIdx.x;
  const int lane = tid & 63;
  const int w = tid >> 6;
  const int fr = lane & 15, fq = lane >> 4;
  const int wr = w >> 2, wc = w & 3;

  const int nwg = gridDim.x;
  const int cpx = nwg >> 3;
  const int wg = (blockIdx.x & 7) * cpx + (blockIdx.x >> 3);
  const int by = wg & 15, bx = wg >> 4;
  const int row0 = by * 128, col0 = bx * (NF * 64);

  const unsigned short* gsrc[NCH];
  int ldsoff[NCH];
#pragma unroll
  for (int c = 0; c < NCH; ++c) {
    int g = tid + 512 * c;
    if (g < 1024) {
      int kk = g >> 9, rr = (g >> 2) & 127, u = g & 3;
      gsrc[c] = A + (size_t)(row0 + rr) * K + kk * 32 + ((u ^ ((rr >> 1) & 3)) * 8);
      ldsoff[c] = kk * 8192 + rr * 64 + u * 16;
    } else {
      int g2 = g - 1024;
      int kk = g2 / (NF * 256);
      int rm = g2 - kk * (NF * 256);
      int rr = rm >> 2, u = rm & 3;
      gsrc[c] = Bt + (size_t)(col0 + rr) * K + kk * 32 + ((u ^ ((rr >> 1) & 3)) * 8);
      ldsoff[c] = 16384 + kk * (NF * 4096) + rr * 64 + u * 16;
    }
  }
  const int urd = (fq ^ ((fr >> 1) & 3)) * 16;
  const int aoffb = (wr * 64 + fr) * 64 + urd;
  const int boffb = 16384 + (wc * NF * 16 + fr) * 64 + urd;

  f32x4 acc[4][NF];
#pragma unroll
  for (int mf = 0; mf < 4; ++mf)
#pragma unroll
    for (int nf = 0; nf < NF; ++nf) acc[mf][nf] = (f32x4)0.f;

  const int NT = K >> 6;

#define ISSUE(c) gload16(gsrc[c] + ktn, smem_ + nbufo + ldsoff[c])
#define RD_A(mf, kk) (*(const short8*)(smem_ + bufo + (kk)*8192 + (mf)*1024 + aoffb))
#define RD_B(nf, kk) (*(const short8*)(smem_ + bufo + (kk)*(NF*4096) + (nf)*1024 + boffb))

  {
    const int ktn = 0, nbufo = 0;
#pragma unroll
    for (int c = 0; c < NCH; ++c) gload16(gsrc[c] + ktn, smem_ + nbufo + ldsoff[c]);
  }

  for (int t = 0; t < NT; ++t) {
    const int bufo = (t & 1) * BUFSZ;
    const int nbufo = bufo ^ BUFSZ;
    const int ktn = (t + 1) * 64;
    const bool pref = (t + 1) < NT;

    asm volatile("s_waitcnt vmcnt(0)" ::: "memory");
    __builtin_amdgcn_s_barrier();

    if (pref) {
#pragma unroll
      for (int c = 0; c < HALF; ++c) ISSUE(c);
    }

    short8 afr[4], bfr[NF];
#pragma unroll
    for (int nf = 0; nf < NF; ++nf) bfr[nf] = RD_B(nf, 0);
#pragma unroll
    for (int mf = 0; mf < 4; ++mf) afr[mf] = RD_A(mf, 0);
    __builtin_amdgcn_s_setprio(1);
#pragma unroll
    for (int mf = 0; mf < 4; ++mf)
#pragma unroll
      for (int nf = 0; nf < NF; ++nf)
        acc[mf][nf] = __builtin_amdgcn_mfma_f32_16x16x32_bf16(afr[mf], bfr[nf], acc[mf][nf], 0, 0, 0);
    __builtin_amdgcn_s_setprio(0);

    if (pref) {
#pragma unroll
      for (int c = HALF; c < NCH; ++c) ISSUE(c);
    }

#pragma unroll
    for (int nf = 0; nf < NF; ++nf) bfr[nf] = RD_B(nf, 1);
#pragma unroll
    for (int mf = 0; mf < 4; ++mf) afr[mf] = RD_A(mf, 1);
    __builtin_amdgcn_s_setprio(1);
#pragma unroll
    for (int mf = 0; mf < 4; ++mf)
#pragma unroll
      for (int nf = 0; nf < NF; ++nf)
        acc[mf][nf] = __builtin_amdgcn_mfma_f32_16x16x32_bf16(afr[mf], bfr[nf], acc[mf][nf], 0, 0, 0);
    __builtin_amdgcn_s_setprio(0);
  }
#undef ISSUE
#undef RD_A
#undef RD_B

#pragma unroll
  for (int mf = 0; mf < 4; ++mf) {
#pragma unroll
    for (int nf = 0; nf < NF; ++nf) {
      const int colb = col0 + wc * NF * 16 + nf * 16 + fr;
      const int rowb = row0 + wr * 64 + mf * 16 + fq * 4;
      const float bs = bias[colb];
      if (EPI == 1) {
#pragma unroll
        for (int j = 0; j < 4; ++j)
          ((unsigned short*)Cout)[(size_t)(rowb + j) * Ncols + colb] =
              f2bf(acc[mf][nf][j] + bs);
      } else {
#pragma unroll
        for (int j = 0; j < 4; ++j) {
          const size_t idx = (size_t)(rowb + j) * Ncols + colb;
          ((float*)Cout)[idx] = acc[mf][nf][j] + bs + resid[idx];
        }
      }
    }
  }
}

// ------- out-proj: 128 x 192, BK=128 free-run GEMM (2x80KB LDS) -------
__global__ __launch_bounds__(512, 2) void gemm_o(
    const unsigned short* __restrict__ A,
    const unsigned short* __restrict__ Bt,
    const float* __restrict__ bias,
    const float* __restrict__ resid,
    float* __restrict__ Cout,
    int K, int Ncols)
{
  constexpr int NF = 3;
  constexpr int BUFSZ = 32768 + NF * 16384;  // 81920
  __shared__ char smem_[2 * BUFSZ];          // 163840
  const int tid = threadIdx.x;
  const int lane = tid & 63;
  const int w = tid >> 6;
  const int fr = lane & 15, fq = lane >> 4;
  const int wr = w >> 2, wc = w & 3;

  const int nwg = gridDim.x;
  const int cpx = nwg >> 3;
  const int wg = (blockIdx.x & 7) * cpx + (blockIdx.x >> 3);
  const int by = wg & 15, bx = wg >> 4;
  const int row0 = by * 128, col0 = bx * (NF * 64);

  const unsigned short* gsrcA[4];
  int loffA[4];
#pragma unroll
  for (int c = 0; c < 4; ++c) {
    int g = tid + 512 * c;
    int kk = g >> 9, rr = (g >> 2) & 127, u = g & 3;
    gsrcA[c] = A + (size_t)(row0 + rr) * K + kk * 32 + ((u ^ ((rr >> 1) & 3)) * 8);
    loffA[c] = kk * 8192 + rr * 64 + u * 16;
  }
  const unsigned short* gsrcB[6];
  int loffB[6];
#pragma unroll
  for (int c = 0; c < 6; ++c) {
    int g = tid + 512 * c;
    int kk = g / 768;
    int rm = g - kk * 768;
    int rr = rm >> 2, u = rm & 3;
    gsrcB[c] = Bt + (size_t)(col0 + rr) * K + kk * 32 + ((u ^ ((rr >> 1) & 3)) * 8);
    loffB[c] = 32768 + kk * 12288 + rr * 64 + u * 16;
  }
  const int urd = (fq ^ ((fr >> 1) & 3)) * 16;
  const int aoffb = (wr * 64 + fr) * 64 + urd;
  const int boffb = 32768 + (wc * 48 + fr) * 64 + urd;

  f32x4 acc[4][NF];
#pragma unroll
  for (int mf = 0; mf < 4; ++mf)
#pragma unroll
    for (int nf = 0; nf < NF; ++nf) acc[mf][nf] = (f32x4)0.f;

  const int NT = K >> 7;

#define RD_A(mf, kk) (*(const short8*)(smem_ + bufo + (kk)*8192 + (mf)*1024 + aoffb))
#define RD_B(nf, kk) (*(const short8*)(smem_ + bufo + (kk)*12288 + (nf)*1024 + boffb))

#pragma unroll
  for (int c = 0; c < 4; ++c) gload16(gsrcA[c], smem_ + loffA[c]);
#pragma unroll
  for (int c = 0; c < 6; ++c) gload16(gsrcB[c], smem_ + loffB[c]);

  for (int t = 0; t < NT; ++t) {
    const int bufo = (t & 1) * BUFSZ;
    const int nbufo = bufo ^ BUFSZ;
    const int ktn = (t + 1) * 128;
    const bool pref = (t + 1) < NT;

    asm volatile("s_waitcnt vmcnt(0)" ::: "memory");
    __builtin_amdgcn_s_barrier();

    if (pref) {
#pragma unroll
      for (int c = 0; c < 4; ++c) gload16(gsrcA[c] + ktn, smem_ + nbufo + loffA[c]);
      gload16(gsrcB[0] + ktn, smem_ + nbufo + loffB[0]);
    }

    short8 afr[4], bfr[NF];
#pragma unroll
    for (int kk = 0; kk < 4; ++kk) {
#pragma unroll
      for (int nf = 0; nf < NF; ++nf) bfr[nf] = RD_B(nf, kk);
#pragma unroll
      for (int mf = 0; mf < 4; ++mf) afr[mf] = RD_A(mf, kk);
      __builtin_amdgcn_s_setprio(1);
#pragma unroll
      for (int mf = 0; mf < 4; ++mf)
#pragma unroll
        for (int nf = 0; nf < NF; ++nf)
          acc[mf][nf] = __builtin_amdgcn_mfma_f32_16x16x32_bf16(afr[mf], bfr[nf], acc[mf][nf], 0, 0, 0);
      __builtin_amdgcn_s_setprio(0);
      if (kk == 0 && pref) {
#pragma unroll
        for (int c = 1; c < 6; ++c) gload16(gsrcB[c] + ktn, smem_ + nbufo + loffB[c]);
      }
    }
  }
#undef RD_A
#undef RD_B

#pragma unroll
  for (int mf = 0; mf < 4; ++mf) {
#pragma unroll
    for (int nf = 0; nf < NF; ++nf) {
      const int colb = col0 + wc * NF * 16 + nf * 16 + fr;
      const int rowb = row0 + wr * 64 + mf * 16 + fq * 4;
      const float bs = bias[colb];
#pragma unroll
      for (int j = 0; j < 4; ++j) {
        const size_t idx = (size_t)(rowb + j) * Ncols + colb;
        Cout[idx] = acc[mf][nf][j] + bs + resid[idx];
      }
    }
  }
}

// ---- attn (fused YaRN rope) + w_out transpose co-tenant blocks ----
__global__ __launch_bounds__(512) void attn_trans_kernel(
    const unsigned short* __restrict__ qkv, const float* __restrict__ sinks,
    const float* __restrict__ cstab, const float* __restrict__ sntab,
    unsigned short* __restrict__ attn,
    const float* __restrict__ w_out, unsigned short* __restrict__ woutT)
{
  __shared__ char smem[45056];
  const int tid = threadIdx.x;
  int bb = blockIdx.x;
  if (bb >= 512) {
    int b = bb - 512;
    int bx = b % 45, by = b / 45;
    const int r0 = by * 64, c0 = bx * 64;
    float (*tile)[65] = (float(*)[65])smem;
    const int c4 = tid & 15, rr = tid >> 4;
#pragma unroll
    for (int p = 0; p < 2; ++p) {
      int row = rr + p * 32;
      float4 v = *(const float4*)&w_out[(size_t)(r0 + row) * 2880 + c0 + c4 * 4];
      tile[row][c4 * 4 + 0] = v.x; tile[row][c4 * 4 + 1] = v.y;
      tile[row][c4 * 4 + 2] = v.z; tile[row][c4 * 4 + 3] = v.w;
    }
    __syncthreads();
    const int rc = tid & 7, cc = tid >> 3;
    unsigned short tmp[8];
#pragma unroll
    for (int i = 0; i < 8; ++i) tmp[i] = f2bf(tile[rc * 8 + i][cc]);
    *(uint4*)&woutT[(size_t)(c0 + cc) * 4096 + r0 + rc * 8] = *(uint4*)tmp;
    return;
  }
  unsigned short* Ks = (unsigned short*)smem;
  unsigned short* Vt = (unsigned short*)(smem + 20480);
  const int lane = tid & 63;
  const int w    = tid >> 6;
  const int qb = bb & 63, kvh = bb >> 6;
  const int q0 = qb * 32;
  const int kb = q0 - 128;
  const int h  = lane >> 5;
  const int ql = lane & 31;

  for (int task = tid; task < 640; task += 512) {
    int r = task >> 2, p = task & 3;
    int j = kb + r; if (j < 0) j = 0;
    const unsigned short* kp = qkv + (size_t)j * QKV_DIM + 4096 + kvh * 64 + p * 8;
    short8 klo = *(const short8*)kp;
    short8 khi = *(const short8*)(kp + 32);
    float cv[8], sv[8];
    *(float4*)&cv[0] = *(const float4*)&cstab[j * 32 + p * 8];
    *(float4*)&cv[4] = *(const float4*)&cstab[j * 32 + p * 8 + 4];
    *(float4*)&sv[0] = *(const float4*)&sntab[j * 32 + p * 8];
    *(float4*)&sv[4] = *(const float4*)&sntab[j * 32 + p * 8 + 4];
    unsigned short nlo[8], nhi[8];
#pragma unroll
    for (int e = 0; e < 8; ++e) {
      float lo = bf2f(((const unsigned short*)&klo)[e]);
      float hi = bf2f(((const unsigned short*)&khi)[e]);
      nlo[e] = f2bf(lo * cv[e] - hi * sv[e]);
      nhi[e] = f2bf(hi * cv[e] + lo * sv[e]);
    }
    *(short8*)&Ks[r * 64 + ((p ^ (r & 7)) * 8)]       = *(short8*)nlo;
    *(short8*)&Ks[r * 64 + (((p + 4) ^ (r & 7)) * 8)] = *(short8*)nhi;
  }
  for (int c = tid; c < 2560; c += 512) {
    int jl = c >> 4;
    int d4 = (c & 15) * 4;
    int j = kb + jl; if (j < 0) j = 0;
    ushort4 v4 = *(const ushort4*)&qkv[(size_t)j * QKV_DIM + 4608 + kvh * 64 + d4];
    const unsigned short* pv = (const unsigned short*)&v4;
#pragma unroll
    for (int t = 0; t < 4; ++t) {
      int d = d4 + t;
      int slot = (jl >> 3) ^ (d & 7);
      Vt[d * 192 + slot * 8 + (jl & 7)] = pv[t];
    }
  }
  const int head = kvh * 8 + w;
  const int i_q = q0 + ql;
  short8 qf[4];
  {
    const unsigned short* qp = qkv + (size_t)i_q * QKV_DIM + head * 64 + h * 8;
#pragma unroll
    for (int ks = 0; ks < 4; ++ks) qf[ks] = *(const short8*)(qp + ks * 16);
#pragma unroll
    for (int p = 0; p < 2; ++p) {
      float cv[8], sv[8];
      int o = i_q * 32 + p * 16 + h * 8;
      *(float4*)&cv[0] = *(const float4*)&cstab[o];
      *(float4*)&cv[4] = *(const float4*)&cstab[o + 4];
      *(float4*)&sv[0] = *(const float4*)&sntab[o];
      *(float4*)&sv[4] = *(const float4*)&sntab[o + 4];
      unsigned short nlo[8], nhi[8];
#pragma unroll
      for (int e = 0; e < 8; ++e) {
        float lo = bf2f(((const unsigned short*)&qf[p])[e]);
        float hi = bf2f(((const unsigned short*)&qf[p + 2])[e]);
        nlo[e] = f2bf(lo * cv[e] - hi * sv[e]);
        nhi[e] = f2bf(hi * cv[e] + lo * sv[e]);
      }
      qf[p]     = *(short8*)nlo;
      qf[p + 2] = *(short8*)nhi;
    }
  }
  __syncthreads();

  const float SC = 0.125f * LOG2E;
  f32x16 oacc0 = (f32x16)(0.f), oacc1 = (f32x16)(0.f);
  float m = -1e30f, l = 0.f;

  const int tstart = qb < 4 ? 4 - qb : 0;
  for (int tt = tstart; tt < 5; ++tt) {
    const int j0 = kb + tt * 32;
    f32x16 sacc = (f32x16)(0.f);
    const int kr = tt * 32 + ql;
#pragma unroll
    for (int ks = 0; ks < 4; ++ks) {
      short8 kf = *(const short8*)&Ks[kr * 64 + (((ks * 2 + h) ^ (kr & 7)) * 8)];
      sacc = __builtin_amdgcn_mfma_f32_32x32x16_bf16(kf, qf[ks], sacc, 0, 0, 0);
    }
    float sc16[16];
    float mt = -INFINITY;
#pragma unroll
    for (int e = 0; e < 16; ++e) {
      int kk = (e & 3) + 8 * (e >> 2) + 4 * h;
      int j = j0 + kk;
      float s2 = sacc[e] * SC;
      bool valid = (j <= i_q) && (j > i_q - 128);
      s2 = valid ? s2 : -INFINITY;
      sc16[e] = s2;
      mt = fmaxf(mt, s2);
    }
    mt = fmaxf(mt, __shfl_xor(mt, 32));
    float mnew = fmaxf(m, mt);
    float r = exp2f(m - mnew);
    l *= r;
    oacc0 *= r;
    oacc1 *= r;
    m = mnew;
    unsigned int wpk[8];
    float ls = 0.f;
#pragma unroll
    for (int e2 = 0; e2 < 8; ++e2) {
      float plo = exp2f(sc16[2 * e2]     - m);
      float phi = exp2f(sc16[2 * e2 + 1] - m);
      ls += plo + phi;
      asm("v_cvt_pk_bf16_f32 %0, %1, %2" : "=v"(wpk[e2]) : "v"(plo), "v"(phi));
    }
    l += ls;
#pragma unroll
    for (int m16 = 0; m16 < 2; ++m16) {
      int go = 2 * m16 + h;
      int gs = 2 * m16 + 1 - h;
      unsigned int x0 = (unsigned int)__shfl_xor((int)wpk[2 * gs],     32);
      unsigned int x1 = (unsigned int)__shfl_xor((int)wpk[2 * gs + 1], 32);
      union { unsigned int u[4]; short8 s; } bu;
      bu.u[0] = h ? x0 : wpk[2 * go];
      bu.u[1] = h ? x1 : wpk[2 * go + 1];
      bu.u[2] = h ? wpk[2 * go]     : x0;
      bu.u[3] = h ? wpk[2 * go + 1] : x1;
      short8 bfrag = bu.s;
#pragma unroll
      for (int dt = 0; dt < 2; ++dt) {
        int d = dt * 32 + ql;
        int slot = (tt * 4 + m16 * 2 + h) ^ (d & 7);
        short8 vf = *(const short8*)&Vt[d * 192 + slot * 8];
        if (dt == 0)
          oacc0 = __builtin_amdgcn_mfma_f32_32x32x16_bf16(vf, bfrag, oacc0, 0, 0, 0);
        else
          oacc1 = __builtin_amdgcn_mfma_f32_32x32x16_bf16(vf, bfrag, oacc1, 0, 0, 0);
      }
    }
  }
  float lt = l + __shfl_xor(l, 32);
  lt += exp2f(sinks[head] * LOG2E - m);
  float inv = 1.f / lt;
  unsigned short* op = attn + (size_t)i_q * 4096 + head * 64;
#pragma unroll
  for (int dt = 0; dt < 2; ++dt) {
#pragma unroll
    for (int g = 0; g < 4; ++g) {
      float f0, f1, f2, f3;
      if (dt == 0) {
        f0 = oacc0[4 * g]; f1 = oacc0[4 * g + 1]; f2 = oacc0[4 * g + 2]; f3 = oacc0[4 * g + 3];
      } else {
        f0 = oacc1[4 * g]; f1 = oacc1[4 * g + 1]; f2 = oacc1[4 * g + 2]; f3 = oacc1[4 * g + 3];
      }
      unsigned int u0, u1;
      asm("v_cvt_pk_bf16_f32 %0, %1, %2" : "=v"(u0) : "v"(f0 * inv), "v"(f1 * inv));
      asm("v_cvt_pk_bf16_f32 %0, %1, %2" : "=v"(u1) : "v"(f2 * inv), "v"(f3 * inv));
      int d = dt * 32 + 8 * g + 4 * h;
      uint2 pr; pr.x = u0; pr.y = u1;
      *(uint2*)(op + d) = pr;
    }
  }
}

extern "C" void kernel_launch(void* const* d_in, const int* in_sizes, int n_in,
                              void* d_out, int out_size, void* d_ws, size_t ws_size,
                              hipStream_t stream)
{
  const float* x      = (const float*)d_in[0];
  const float* nscale = (const float*)d_in[1];
  const float* w_qkv  = (const float*)d_in[2];
  const float* b_qkv  = (const float*)d_in[3];
  const float* sinks  = (const float*)d_in[4];
  const float* w_out  = (const float*)d_in[5];
  const float* b_out  = (const float*)d_in[6];

  char* ws = (char*)d_ws;
  unsigned short* t_bf  = (unsigned short*)(ws);                 // [2048][2880] bf16
  unsigned short* wqkvT = (unsigned short*)(ws + 11796480);      // [5120][2880] bf16
  unsigned short* qkv   = (unsigned short*)(ws + 41287680);      // [2048][5120] bf16
  unsigned short* attn  = (unsigned short*)(ws + 62259200);      // [2048][4096] bf16
  unsigned short* woutT = (unsigned short*)(ws + 79036416);      // [2880][4096] bf16
  float* cstab          = (float*)(ws + 102629376);              // [2048][32] f32
  float* sntab          = (float*)(ws + 102891520);              // [2048][32] f32

  prep1_kernel<<<5712, 256, 0, stream>>>(w_qkv, wqkvT, x, nscale, t_bf, cstab, sntab);
  gemm8<5, 1><<<256, 512, 0, stream>>>(t_bf, wqkvT, b_qkv, nullptr, (void*)qkv, 2880, 5120);
  attn_trans_kernel<<<3392, 512, 0, stream>>>(qkv, sinks, cstab, sntab, attn, w_out, woutT);
  gemm_o<<<240, 512, 0, stream>>>(attn, woutT, b_out, x, (float*)d_out, 4096, 2880);
}